// Round 1
// baseline (13698.279 us; speedup 1.0000x reference)
//
#include <hip/hip_runtime.h>

#define B_ 4
#define L_ 1024
#define H_ 32
#define HKV_ 8
#define DH_ 128
#define SCALE_ 0.08838834764831845f
#define NEGF (-1e30f)
#define KEEP_ 512
#define O_ELEMS (B_*L_*H_*DH_)          // 16777216
#define CACHE_ELEMS (8192*HKV_*DH_)     // 8388608

// ---------------- full causal attention (fp32 flash) ----------------
// grid: 4096 blocks = (b, h, qt); 256 threads. TQ=32, TK=32.
__global__ __launch_bounds__(256, 2)
void attn_kernel(const float* __restrict__ q, const float* __restrict__ k,
                 const float* __restrict__ v, float* __restrict__ o)
{
    __shared__ float qs[32][128];      // q tile
    __shared__ float kT[128][33];      // k tile transposed [d][k]
    __shared__ float vt[32][132];      // v tile [k][d], stride 132 (16B aligned, 2-way reads)
    __shared__ float stile[32][33];    // p-tilde
    __shared__ float alpha_s[32];
    __shared__ float l_s[32];

    int bid = blockIdx.x;
    int qt = 31 - (bid & 31);          // heavy tiles first (tail balance)
    int h  = (bid >> 5) & 31;
    int b  = bid >> 10;
    int hkv = h >> 2;
    int t = threadIdx.x;

    // stage q tile (32 rows x 128)
    for (int i = 0; i < 4; ++i) {
        int pos = t + 256 * i;          // float4 index 0..1023
        int r = pos >> 5;
        int d4 = (pos & 31) << 2;
        int n = b * L_ + qt * 32 + r;
        float4 val = *(const float4*)&q[((size_t)n * H_ + h) * DH_ + d4];
        *(float4*)&qs[r][d4] = val;
    }

    int lk  = t & 31;       // score k index
    int qg  = t >> 5;       // score q-group (rows qg*4+i)
    int d2  = (t & 63) * 2; // PV d pair
    int qg4 = t >> 6;       // PV q-group (rows qg4*8+j)

    float m_reg[4], l_reg[4];
    #pragma unroll
    for (int i = 0; i < 4; ++i) { m_reg[i] = NEGF; l_reg[i] = 0.f; }
    float acc_o[8][2];
    #pragma unroll
    for (int j = 0; j < 8; ++j) { acc_o[j][0] = 0.f; acc_o[j][1] = 0.f; }

    int nkt = qt + 1;   // causal tile skip
    for (int kt = 0; kt < nkt; ++kt) {
        __syncthreads();   // protect kT/vt/stile from previous iteration readers
        // stage k (transposed) + v tile
        for (int i = 0; i < 4; ++i) {
            int pos = t + 256 * i;
            int r = pos >> 5;
            int d4 = (pos & 31) << 2;
            int n = b * L_ + kt * 32 + r;
            float4 kv4 = *(const float4*)&k[((size_t)n * HKV_ + hkv) * DH_ + d4];
            kT[d4 + 0][r] = kv4.x; kT[d4 + 1][r] = kv4.y;
            kT[d4 + 2][r] = kv4.z; kT[d4 + 3][r] = kv4.w;
            float4 vv4 = *(const float4*)&v[((size_t)n * HKV_ + hkv) * DH_ + d4];
            *(float4*)&vt[r][d4] = vv4;
        }
        __syncthreads();

        // scores: 4 per thread (rows qg*4+i, col lk)
        float acc[4] = {0.f, 0.f, 0.f, 0.f};
        for (int d = 0; d < 128; d += 4) {
            float k0 = kT[d + 0][lk], k1 = kT[d + 1][lk];
            float k2 = kT[d + 2][lk], k3 = kT[d + 3][lk];
            #pragma unroll
            for (int i = 0; i < 4; ++i) {
                float4 q4 = *(const float4*)&qs[qg * 4 + i][d];
                acc[i] += q4.x * k0 + q4.y * k1 + q4.z * k2 + q4.w * k3;
            }
        }
        int kabs = kt * 32 + lk;
        #pragma unroll
        for (int i = 0; i < 4; ++i) {
            int qabs = qt * 32 + qg * 4 + i;
            acc[i] = (kabs <= qabs) ? acc[i] * SCALE_ : NEGF;
        }
        // online softmax update; 32-lane shuffle groups own rows
        #pragma unroll
        for (int i = 0; i < 4; ++i) {
            float mt = acc[i];
            for (int off = 16; off > 0; off >>= 1) mt = fmaxf(mt, __shfl_xor(mt, off));
            float m_new = fmaxf(m_reg[i], mt);
            float p = __expf(acc[i] - m_new);
            float sum = p;
            for (int off = 16; off > 0; off >>= 1) sum += __shfl_xor(sum, off);
            float alpha = __expf(m_reg[i] - m_new);
            l_reg[i] = l_reg[i] * alpha + sum;
            m_reg[i] = m_new;
            stile[qg * 4 + i][lk] = p;
            if (lk == 0) alpha_s[qg * 4 + i] = alpha;
        }
        __syncthreads();

        // PV accumulate: thread owns rows qg4*8+j, cols d2,d2+1
        #pragma unroll
        for (int j = 0; j < 8; ++j) {
            float a = alpha_s[qg4 * 8 + j];
            acc_o[j][0] *= a; acc_o[j][1] *= a;
        }
        for (int kk = 0; kk < 32; ++kk) {
            float2 v2 = *(const float2*)&vt[kk][d2];
            #pragma unroll
            for (int j = 0; j < 8; ++j) {
                float p = stile[qg4 * 8 + j][kk];
                acc_o[j][0] += p * v2.x;
                acc_o[j][1] += p * v2.y;
            }
        }
    }
    __syncthreads();
    if (lk == 0) {
        #pragma unroll
        for (int i = 0; i < 4; ++i) l_s[qg * 4 + i] = l_reg[i];
    }
    __syncthreads();
    #pragma unroll
    for (int j = 0; j < 8; ++j) {
        int r = qg4 * 8 + j;
        float inv = 1.0f / l_s[r];
        int n = b * L_ + qt * 32 + r;
        float2 res;
        res.x = acc_o[j][0] * inv;
        res.y = acc_o[j][1] * inv;
        *(float2*)&o[((size_t)n * H_ + h) * DH_ + d2] = res;
    }
}

// ---------------- importance (two-pass flash over sample rows) ----------------
// grid: 512 blocks = (b, h, qtl in 0..3 -> abs q-tile 28+qtl); 256 threads.
__global__ __launch_bounds__(256, 2)
void importance_kernel(const float* __restrict__ q, const float* __restrict__ k,
                       float* __restrict__ imp)
{
    __shared__ float qs[32][128];
    __shared__ float kT[128][33];
    __shared__ float tmp[8][32];
    __shared__ float imp_full[1024];

    int bid = blockIdx.x;
    int qtl = bid & 3;
    int h   = (bid >> 2) & 31;
    int b   = bid >> 7;
    int hkv = h >> 2;
    int qta = 28 + qtl;
    int t = threadIdx.x;

    for (int i = t; i < 1024; i += 256) imp_full[i] = 0.f;

    for (int i = 0; i < 4; ++i) {
        int pos = t + 256 * i;
        int r = pos >> 5;
        int d4 = (pos & 31) << 2;
        int n = b * L_ + qta * 32 + r;
        float4 val = *(const float4*)&q[((size_t)n * H_ + h) * DH_ + d4];
        *(float4*)&qs[r][d4] = val;
    }

    int lk = t & 31;
    int qg = t >> 5;
    int nkt = qta + 1;

    float m_reg[4], l_reg[4];
    #pragma unroll
    for (int i = 0; i < 4; ++i) { m_reg[i] = NEGF; l_reg[i] = 0.f; }

    for (int pass = 0; pass < 2; ++pass) {
        for (int kt = 0; kt < nkt; ++kt) {
            __syncthreads();
            for (int i = 0; i < 4; ++i) {
                int pos = t + 256 * i;
                int r = pos >> 5;
                int d4 = (pos & 31) << 2;
                int n = b * L_ + kt * 32 + r;
                float4 kv4 = *(const float4*)&k[((size_t)n * HKV_ + hkv) * DH_ + d4];
                kT[d4 + 0][r] = kv4.x; kT[d4 + 1][r] = kv4.y;
                kT[d4 + 2][r] = kv4.z; kT[d4 + 3][r] = kv4.w;
            }
            __syncthreads();
            float acc[4] = {0.f, 0.f, 0.f, 0.f};
            for (int d = 0; d < 128; d += 4) {
                float k0 = kT[d + 0][lk], k1 = kT[d + 1][lk];
                float k2 = kT[d + 2][lk], k3 = kT[d + 3][lk];
                #pragma unroll
                for (int i = 0; i < 4; ++i) {
                    float4 q4 = *(const float4*)&qs[qg * 4 + i][d];
                    acc[i] += q4.x * k0 + q4.y * k1 + q4.z * k2 + q4.w * k3;
                }
            }
            int kabs = kt * 32 + lk;
            #pragma unroll
            for (int i = 0; i < 4; ++i) {
                int qabs = qta * 32 + qg * 4 + i;
                acc[i] = (kabs <= qabs) ? acc[i] * SCALE_ : NEGF;
            }
            if (pass == 0) {
                #pragma unroll
                for (int i = 0; i < 4; ++i) {
                    float mt = acc[i];
                    for (int off = 16; off > 0; off >>= 1) mt = fmaxf(mt, __shfl_xor(mt, off));
                    float m_new = fmaxf(m_reg[i], mt);
                    float p = expf(acc[i] - m_new);
                    float sum = p;
                    for (int off = 16; off > 0; off >>= 1) sum += __shfl_xor(sum, off);
                    float alpha = expf(m_reg[i] - m_new);
                    l_reg[i] = l_reg[i] * alpha + sum;
                    m_reg[i] = m_new;
                }
            } else {
                float psum = 0.f;
                #pragma unroll
                for (int i = 0; i < 4; ++i)
                    psum += expf(acc[i] - m_reg[i]) / l_reg[i];
                tmp[qg][lk] = psum;
                __syncthreads();
                if (t < 32) {
                    float s = 0.f;
                    #pragma unroll
                    for (int g = 0; g < 8; ++g) s += tmp[g][t];
                    imp_full[kt * 32 + t] = s;
                }
            }
        }
    }
    __syncthreads();
    for (int c = t; c < 1024; c += 256)
        atomicAdd(&imp[b * L_ + c], imp_full[c]);
}

// ---------------- top-k 512 of 1024 per batch ----------------
__global__ void topk_kernel(const float* __restrict__ imp, int* __restrict__ keep)
{
    __shared__ float vals[1024];
    __shared__ int   idxs[1024];
    int b = blockIdx.x;
    int t = threadIdx.x;   // 512 threads
    for (int i = t; i < 1024; i += 512) { vals[i] = imp[b * L_ + i]; idxs[i] = i; }

    // bitonic sort DESC by (value desc, idx asc)
    for (int size = 2; size <= 1024; size <<= 1) {
        for (int stride = size >> 1; stride > 0; stride >>= 1) {
            __syncthreads();
            for (int i = t; i < 1024; i += 512) {
                int j = i ^ stride;
                if (j > i) {
                    float vi = vals[i], vj = vals[j];
                    int ii = idxs[i], ij = idxs[j];
                    bool j_before_i = (vj > vi) || (vj == vi && ij < ii);
                    bool descRegion = ((i & size) == 0);
                    bool doSwap = descRegion ? j_before_i : !j_before_i;
                    if (doSwap) {
                        vals[i] = vj; vals[j] = vi;
                        idxs[i] = ij; idxs[j] = ii;
                    }
                }
            }
        }
    }
    __syncthreads();
    // sort first 512 indices ascending
    for (int size = 2; size <= 512; size <<= 1) {
        for (int stride = size >> 1; stride > 0; stride >>= 1) {
            __syncthreads();
            int i = t, j = t ^ stride;
            if (j > i) {
                int a = idxs[i], bb = idxs[j];
                bool ascRegion = ((i & size) == 0);
                bool doSwap = ascRegion ? (a > bb) : (a < bb);
                if (doSwap) { idxs[i] = bb; idxs[j] = a; }
            }
        }
    }
    __syncthreads();
    keep[b * KEEP_ + t] = idxs[t];
}

// ---------------- scatter kept k/v rows into caches ----------------
__global__ void scatter_kernel(const float* __restrict__ kin, const float* __restrict__ vin,
                               const int* __restrict__ keep, const int* __restrict__ slot_mapping,
                               float* __restrict__ kc_out, float* __restrict__ vc_out)
{
    int bid = blockIdx.x;          // 2048 = b*512 + j
    int b = bid >> 9, j = bid & 511;
    int src = b * L_ + keep[b * KEEP_ + j];
    int dst = slot_mapping[b * L_ + j];
    int t = threadIdx.x;           // 256, float4 each = 1024 floats
    float4 kv = *(const float4*)&kin[(size_t)src * 1024 + t * 4];
    *(float4*)&kc_out[(size_t)dst * 1024 + t * 4] = kv;
    float4 vv = *(const float4*)&vin[(size_t)src * 1024 + t * 4];
    *(float4*)&vc_out[(size_t)dst * 1024 + t * 4] = vv;
}

extern "C" void kernel_launch(void* const* d_in, const int* in_sizes, int n_in,
                              void* d_out, int out_size, void* d_ws, size_t ws_size,
                              hipStream_t stream)
{
    const float* q = (const float*)d_in[0];
    const float* k = (const float*)d_in[1];
    const float* v = (const float*)d_in[2];
    const float* k_cache = (const float*)d_in[3];
    const float* v_cache = (const float*)d_in[4];
    const int* slot_mapping = (const int*)d_in[5];

    float* o = (float*)d_out;
    float* kc_out = o + O_ELEMS;
    float* vc_out = kc_out + CACHE_ELEMS;

    float* imp = (float*)d_ws;                 // B*L floats
    int* keep = (int*)(imp + B_ * L_);         // B*512 ints

    hipMemcpyAsync(kc_out, k_cache, (size_t)CACHE_ELEMS * 4, hipMemcpyDeviceToDevice, stream);
    hipMemcpyAsync(vc_out, v_cache, (size_t)CACHE_ELEMS * 4, hipMemcpyDeviceToDevice, stream);
    hipMemsetAsync(imp, 0, B_ * L_ * 4, stream);

    attn_kernel<<<dim3(4096), dim3(256), 0, stream>>>(q, k, v, o);
    importance_kernel<<<dim3(512), dim3(256), 0, stream>>>(q, k, imp);
    topk_kernel<<<dim3(4), dim3(512), 0, stream>>>(imp, keep);
    scatter_kernel<<<dim3(2048), dim3(256), 0, stream>>>(k, v, keep, slot_mapping, kc_out, vc_out);
}

// Round 2
// 599.632 us; speedup vs baseline: 22.8445x; 22.8445x over previous
//
#include <hip/hip_runtime.h>

#define B_ 4
#define L_ 1024
#define H_ 32
#define HKV_ 8
#define DH_ 128
#define SCALE_ 0.08838834764831845f
#define NEGF (-1e30f)
#define KEEP_ 512
#define O_ELEMS (B_*L_*H_*DH_)          // 16777216
#define CACHE_ELEMS (8192*HKV_*DH_)     // 8388608

typedef short short8 __attribute__((ext_vector_type(8)));
typedef float floatx4 __attribute__((ext_vector_type(4)));

__device__ inline unsigned short bf16r(float x) {
    unsigned int u = __builtin_bit_cast(unsigned int, x);
    u += 0x7fffu + ((u >> 16) & 1u);
    return (unsigned short)(u >> 16);
}
__device__ inline float bf16tof(unsigned short h) {
    unsigned int u = ((unsigned int)h) << 16;
    return __builtin_bit_cast(float, u);
}

// ---------------- full causal attention, bf16 MFMA flash ----------------
// grid 2048 = (b,h,qt); 256 thr = 4 waves; TQ=64 (16 rows/wave), TK=64.
__global__ __launch_bounds__(256, 3)
void attn_mfma(const float* __restrict__ qp, const float* __restrict__ kp,
               const float* __restrict__ vp, float* __restrict__ op)
{
    __shared__ unsigned short k_lds[64 * 136];   // [kcol][dim], dim contig, pad->136
    __shared__ unsigned short vT[128 * 72];      // [d][row blocks], XOR-swizzled 16B blocks
    __shared__ unsigned short p_lds[4 * 16 * 72];// per-wave P tile [m][kcol]

    int bid = blockIdx.x;
    int qt = bid & 15;
    int h  = (bid >> 4) & 31;
    int b  = bid >> 9;
    int hkv = h >> 2;
    int t = threadIdx.x;
    int w = t >> 6;
    int l = t & 63;
    int lm = l & 15;
    int hq = l >> 4;

    // Q A-frags in registers, SCALE_ folded in. A[m=lm][k=hq*8+j+32c]
    short8 aq[4];
    {
        const float* qbase = qp + ((size_t)(b * L_ + qt * 64 + w * 16 + lm) * H_ + h) * DH_;
        #pragma unroll
        for (int c = 0; c < 4; ++c) {
            int dc = hq * 8 + 32 * c;
            float e[8];
            *(float4*)&e[0] = *(const float4*)(qbase + dc);
            *(float4*)&e[4] = *(const float4*)(qbase + dc + 4);
            short8 fr;
            #pragma unroll
            for (int j = 0; j < 8; ++j) fr[j] = (short)bf16r(e[j] * SCALE_);
            aq[c] = fr;
        }
    }

    floatx4 O[8];
    #pragma unroll
    for (int n = 0; n < 8; ++n) O[n] = (floatx4){0.f, 0.f, 0.f, 0.f};
    float m_run[4], l_run[4];
    #pragma unroll
    for (int r = 0; r < 4; ++r) { m_run[r] = NEGF; l_run[r] = 0.f; }

    for (int kt = 0; kt <= qt; ++kt) {
        __syncthreads();   // prior tile's LDS readers done before restage
        // stage K: [col][dim] natural layout
        #pragma unroll
        for (int i = 0; i < 8; ++i) {
            int pos = t + 256 * i;
            int col = pos >> 5;
            int d4  = (pos & 31) << 2;
            float4 kv = *(const float4*)&kp[((size_t)(b * L_ + kt * 64 + col) * HKV_ + hkv) * DH_ + d4];
            ushort4 pk;
            pk.x = bf16r(kv.x); pk.y = bf16r(kv.y); pk.z = bf16r(kv.z); pk.w = bf16r(kv.w);
            *(ushort4*)&k_lds[col * 136 + d4] = pk;
        }
        // stage V transposed: thread reads 4 rows x float4 (coalesced), writes b64 row-packs
        #pragma unroll
        for (int it = 0; it < 2; ++it) {
            int d4 = (t & 31) << 2;
            int rb = ((t >> 5) << 2) + 32 * it;
            const float* vbase = &vp[((size_t)(b * L_ + kt * 64 + rb) * HKV_ + hkv) * DH_ + d4];
            float e0[4], e1[4], e2[4], e3[4];
            *(float4*)e0 = *(const float4*)(vbase);
            *(float4*)e1 = *(const float4*)(vbase + (size_t)HKV_ * DH_);
            *(float4*)e2 = *(const float4*)(vbase + (size_t)2 * HKV_ * DH_);
            *(float4*)e3 = *(const float4*)(vbase + (size_t)3 * HKV_ * DH_);
            #pragma unroll
            for (int ii = 0; ii < 4; ++ii) {
                int d = d4 + ii;
                ushort4 pk;
                pk.x = bf16r(e0[ii]); pk.y = bf16r(e1[ii]);
                pk.z = bf16r(e2[ii]); pk.w = bf16r(e3[ii]);
                int idx = d * 72 + (((rb >> 3) ^ ((d >> 2) & 7)) << 3) + (rb & 7);
                *(ushort4*)&vT[idx] = pk;
            }
        }
        __syncthreads();

        // QK^T: S[c] rows m=hq*4+r, cols c*16+lm
        floatx4 S[4];
        #pragma unroll
        for (int c = 0; c < 4; ++c) S[c] = (floatx4){0.f, 0.f, 0.f, 0.f};
        #pragma unroll
        for (int kc = 0; kc < 4; ++kc) {
            #pragma unroll
            for (int c = 0; c < 4; ++c) {
                short8 bk = *(const short8*)&k_lds[(c * 16 + lm) * 136 + kc * 32 + hq * 8];
                S[c] = __builtin_amdgcn_mfma_f32_16x16x32_bf16(aq[kc], bk, S[c], 0, 0, 0);
            }
        }
        if (kt == qt) {   // diagonal tile mask (uniform branch)
            #pragma unroll
            for (int c = 0; c < 4; ++c) {
                int kabs = kt * 64 + c * 16 + lm;
                #pragma unroll
                for (int r = 0; r < 4; ++r) {
                    int qabs = qt * 64 + w * 16 + hq * 4 + r;
                    if (kabs > qabs) S[c][r] = NEGF;
                }
            }
        }
        // online softmax (rows live in 16-lane groups)
        #pragma unroll
        for (int r = 0; r < 4; ++r) {
            float mx = fmaxf(fmaxf(S[0][r], S[1][r]), fmaxf(S[2][r], S[3][r]));
            mx = fmaxf(mx, __shfl_xor(mx, 1));
            mx = fmaxf(mx, __shfl_xor(mx, 2));
            mx = fmaxf(mx, __shfl_xor(mx, 4));
            mx = fmaxf(mx, __shfl_xor(mx, 8));
            float m_new = fmaxf(m_run[r], mx);
            float p0 = __expf(S[0][r] - m_new);
            float p1 = __expf(S[1][r] - m_new);
            float p2 = __expf(S[2][r] - m_new);
            float p3 = __expf(S[3][r] - m_new);
            int prow = (w * 16 + hq * 4 + r) * 72;
            p_lds[prow + 0 + lm]  = bf16r(p0);
            p_lds[prow + 16 + lm] = bf16r(p1);
            p_lds[prow + 32 + lm] = bf16r(p2);
            p_lds[prow + 48 + lm] = bf16r(p3);
            float sum = p0 + p1 + p2 + p3;
            sum += __shfl_xor(sum, 1);
            sum += __shfl_xor(sum, 2);
            sum += __shfl_xor(sum, 4);
            sum += __shfl_xor(sum, 8);
            float alpha = __expf(m_run[r] - m_new);
            l_run[r] = l_run[r] * alpha + sum;
            m_run[r] = m_new;
            #pragma unroll
            for (int n = 0; n < 8; ++n) O[n][r] *= alpha;
        }
        // stop compiler reordering the cross-lane p_lds write->read
        asm volatile("" ::: "memory");
        short8 aP0 = *(const short8*)&p_lds[(w * 16 + lm) * 72 + hq * 8];
        short8 aP1 = *(const short8*)&p_lds[(w * 16 + lm) * 72 + hq * 8 + 32];
        #pragma unroll
        for (int n = 0; n < 8; ++n) {
            int d = n * 16 + lm;
            int sw = (d >> 2) & 7;
            short8 v0 = *(const short8*)&vT[d * 72 + ((hq ^ sw) << 3)];
            O[n] = __builtin_amdgcn_mfma_f32_16x16x32_bf16(aP0, v0, O[n], 0, 0, 0);
            short8 v1 = *(const short8*)&vT[d * 72 + (((hq + 4) ^ sw) << 3)];
            O[n] = __builtin_amdgcn_mfma_f32_16x16x32_bf16(aP1, v1, O[n], 0, 0, 0);
        }
    }
    // epilogue
    float inv[4];
    #pragma unroll
    for (int r = 0; r < 4; ++r) inv[r] = 1.0f / l_run[r];
    #pragma unroll
    for (int r = 0; r < 4; ++r) {
        float* obase = op + ((size_t)(b * L_ + qt * 64 + w * 16 + hq * 4 + r) * H_ + h) * DH_ + lm;
        #pragma unroll
        for (int n = 0; n < 8; ++n)
            obase[n * 16] = O[n][r] * inv[r];
    }
}

// ---------------- importance: split-bf16 MFMA (fp32-class logits) ----------------
// grid 256 = (b,h,qts in 0..1); two-pass (m,l then column sums).
__global__ __launch_bounds__(256, 2)
void importance_mfma(const float* __restrict__ qp, const float* __restrict__ kp,
                     float* __restrict__ imp)
{
    __shared__ unsigned short khi[64 * 136];
    __shared__ unsigned short klo[64 * 136];
    __shared__ float imp_loc[1024];

    int bid = blockIdx.x;
    int qts = bid & 1;
    int h   = (bid >> 1) & 31;
    int b   = bid >> 6;
    int hkv = h >> 2;
    int t = threadIdx.x;
    int w = t >> 6;
    int l = t & 63;
    int lm = l & 15;
    int hq = l >> 4;

    for (int i = t; i < 1024; i += 256) imp_loc[i] = 0.f;

    int q0 = 896 + qts * 64;
    int ktd = q0 >> 6;   // diagonal tile index

    // q hi/lo A-frags (scale folded pre-split)
    short8 aqh[4], aql[4];
    {
        const float* qbase = qp + ((size_t)(b * L_ + q0 + w * 16 + lm) * H_ + h) * DH_;
        #pragma unroll
        for (int c = 0; c < 4; ++c) {
            int dc = hq * 8 + 32 * c;
            float e[8];
            *(float4*)&e[0] = *(const float4*)(qbase + dc);
            *(float4*)&e[4] = *(const float4*)(qbase + dc + 4);
            short8 fh, fl;
            #pragma unroll
            for (int j = 0; j < 8; ++j) {
                float xs = e[j] * SCALE_;
                unsigned short hb = bf16r(xs);
                fh[j] = (short)hb;
                fl[j] = (short)bf16r(xs - bf16tof(hb));
            }
            aqh[c] = fh; aql[c] = fl;
        }
    }

    float m_run[4], l_run[4];
    #pragma unroll
    for (int r = 0; r < 4; ++r) { m_run[r] = NEGF; l_run[r] = 0.f; }

    for (int pass = 0; pass < 2; ++pass) {
        float invl[4];
        if (pass == 1) {
            #pragma unroll
            for (int r = 0; r < 4; ++r) invl[r] = 1.0f / l_run[r];
        }
        for (int kt = 0; kt <= ktd; ++kt) {
            __syncthreads();
            #pragma unroll
            for (int i = 0; i < 8; ++i) {
                int pos = t + 256 * i;
                int col = pos >> 5;
                int d4  = (pos & 31) << 2;
                float4 kv = *(const float4*)&kp[((size_t)(b * L_ + kt * 64 + col) * HKV_ + hkv) * DH_ + d4];
                ushort4 ph, pl;
                ph.x = bf16r(kv.x); pl.x = bf16r(kv.x - bf16tof(ph.x));
                ph.y = bf16r(kv.y); pl.y = bf16r(kv.y - bf16tof(ph.y));
                ph.z = bf16r(kv.z); pl.z = bf16r(kv.z - bf16tof(ph.z));
                ph.w = bf16r(kv.w); pl.w = bf16r(kv.w - bf16tof(ph.w));
                *(ushort4*)&khi[col * 136 + d4] = ph;
                *(ushort4*)&klo[col * 136 + d4] = pl;
            }
            __syncthreads();

            floatx4 S[4];
            #pragma unroll
            for (int c = 0; c < 4; ++c) S[c] = (floatx4){0.f, 0.f, 0.f, 0.f};
            #pragma unroll
            for (int kc = 0; kc < 4; ++kc) {
                #pragma unroll
                for (int c = 0; c < 4; ++c) {
                    int kidx = (c * 16 + lm) * 136 + kc * 32 + hq * 8;
                    short8 bh = *(const short8*)&khi[kidx];
                    short8 bl = *(const short8*)&klo[kidx];
                    S[c] = __builtin_amdgcn_mfma_f32_16x16x32_bf16(aqh[kc], bh, S[c], 0, 0, 0);
                    S[c] = __builtin_amdgcn_mfma_f32_16x16x32_bf16(aqh[kc], bl, S[c], 0, 0, 0);
                    S[c] = __builtin_amdgcn_mfma_f32_16x16x32_bf16(aql[kc], bh, S[c], 0, 0, 0);
                }
            }
            if (kt == ktd) {
                #pragma unroll
                for (int c = 0; c < 4; ++c) {
                    int kabs = kt * 64 + c * 16 + lm;
                    #pragma unroll
                    for (int r = 0; r < 4; ++r) {
                        int qabs = q0 + w * 16 + hq * 4 + r;
                        if (kabs > qabs) S[c][r] = NEGF;
                    }
                }
            }
            if (pass == 0) {
                #pragma unroll
                for (int r = 0; r < 4; ++r) {
                    float mx = fmaxf(fmaxf(S[0][r], S[1][r]), fmaxf(S[2][r], S[3][r]));
                    mx = fmaxf(mx, __shfl_xor(mx, 1));
                    mx = fmaxf(mx, __shfl_xor(mx, 2));
                    mx = fmaxf(mx, __shfl_xor(mx, 4));
                    mx = fmaxf(mx, __shfl_xor(mx, 8));
                    float m_new = fmaxf(m_run[r], mx);
                    float sum = __expf(S[0][r] - m_new) + __expf(S[1][r] - m_new)
                              + __expf(S[2][r] - m_new) + __expf(S[3][r] - m_new);
                    sum += __shfl_xor(sum, 1);
                    sum += __shfl_xor(sum, 2);
                    sum += __shfl_xor(sum, 4);
                    sum += __shfl_xor(sum, 8);
                    float alpha = __expf(m_run[r] - m_new);
                    l_run[r] = l_run[r] * alpha + sum;
                    m_run[r] = m_new;
                }
            } else {
                #pragma unroll
                for (int c = 0; c < 4; ++c) {
                    float cs = 0.f;
                    #pragma unroll
                    for (int r = 0; r < 4; ++r)
                        cs += __expf(S[c][r] - m_run[r]) * invl[r];
                    cs += __shfl_xor(cs, 16);
                    cs += __shfl_xor(cs, 32);
                    if (hq == 0) atomicAdd(&imp_loc[kt * 64 + c * 16 + lm], cs);
                }
            }
        }
    }
    __syncthreads();
    for (int i = t; i < 1024; i += 256)
        atomicAdd(&imp[b * L_ + i], imp_loc[i]);
}

// ---------------- top-k 512 of 1024 per batch ----------------
__global__ void topk_kernel(const float* __restrict__ imp, int* __restrict__ keep)
{
    __shared__ float vals[1024];
    __shared__ int   idxs[1024];
    int b = blockIdx.x;
    int t = threadIdx.x;   // 512 threads
    for (int i = t; i < 1024; i += 512) { vals[i] = imp[b * L_ + i]; idxs[i] = i; }

    for (int size = 2; size <= 1024; size <<= 1) {
        for (int stride = size >> 1; stride > 0; stride >>= 1) {
            __syncthreads();
            for (int i = t; i < 1024; i += 512) {
                int j = i ^ stride;
                if (j > i) {
                    float vi = vals[i], vj = vals[j];
                    int ii = idxs[i], ij = idxs[j];
                    bool j_before_i = (vj > vi) || (vj == vi && ij < ii);
                    bool descRegion = ((i & size) == 0);
                    bool doSwap = descRegion ? j_before_i : !j_before_i;
                    if (doSwap) {
                        vals[i] = vj; vals[j] = vi;
                        idxs[i] = ij; idxs[j] = ii;
                    }
                }
            }
        }
    }
    __syncthreads();
    for (int size = 2; size <= 512; size <<= 1) {
        for (int stride = size >> 1; stride > 0; stride >>= 1) {
            __syncthreads();
            int i = t, j = t ^ stride;
            if (j > i) {
                int a = idxs[i], bb = idxs[j];
                bool ascRegion = ((i & size) == 0);
                bool doSwap = ascRegion ? (a > bb) : (a < bb);
                if (doSwap) { idxs[i] = bb; idxs[j] = a; }
            }
        }
    }
    __syncthreads();
    keep[b * KEEP_ + t] = idxs[t];
}

// ---------------- scatter kept k/v rows into caches ----------------
__global__ void scatter_kernel(const float* __restrict__ kin, const float* __restrict__ vin,
                               const int* __restrict__ keep, const int* __restrict__ slot_mapping,
                               float* __restrict__ kc_out, float* __restrict__ vc_out)
{
    int bid = blockIdx.x;          // 2048 = b*512 + j
    int b = bid >> 9, j = bid & 511;
    int src = b * L_ + keep[b * KEEP_ + j];
    int dst = slot_mapping[b * L_ + j];
    int t = threadIdx.x;           // 256, float4 each = 1024 floats
    float4 kv = *(const float4*)&kin[(size_t)src * 1024 + t * 4];
    *(float4*)&kc_out[(size_t)dst * 1024 + t * 4] = kv;
    float4 vv = *(const float4*)&vin[(size_t)src * 1024 + t * 4];
    *(float4*)&vc_out[(size_t)dst * 1024 + t * 4] = vv;
}

extern "C" void kernel_launch(void* const* d_in, const int* in_sizes, int n_in,
                              void* d_out, int out_size, void* d_ws, size_t ws_size,
                              hipStream_t stream)
{
    const float* q = (const float*)d_in[0];
    const float* k = (const float*)d_in[1];
    const float* v = (const float*)d_in[2];
    const float* k_cache = (const float*)d_in[3];
    const float* v_cache = (const float*)d_in[4];
    const int* slot_mapping = (const int*)d_in[5];

    float* o = (float*)d_out;
    float* kc_out = o + O_ELEMS;
    float* vc_out = kc_out + CACHE_ELEMS;

    float* imp = (float*)d_ws;                 // B*L floats
    int* keep = (int*)(imp + B_ * L_);         // B*512 ints

    hipMemcpyAsync(kc_out, k_cache, (size_t)CACHE_ELEMS * 4, hipMemcpyDeviceToDevice, stream);
    hipMemcpyAsync(vc_out, v_cache, (size_t)CACHE_ELEMS * 4, hipMemcpyDeviceToDevice, stream);
    hipMemsetAsync(imp, 0, B_ * L_ * 4, stream);

    attn_mfma<<<dim3(2048), dim3(256), 0, stream>>>(q, k, v, o);
    importance_mfma<<<dim3(256), dim3(256), 0, stream>>>(q, k, imp);
    topk_kernel<<<dim3(4), dim3(512), 0, stream>>>(imp, keep);
    scatter_kernel<<<dim3(2048), dim3(256), 0, stream>>>(k, v, keep, slot_mapping, kc_out, vc_out);
}

// Round 4
// 484.010 us; speedup vs baseline: 28.3017x; 1.2389x over previous
//
#include <hip/hip_runtime.h>

#define B_ 4
#define L_ 1024
#define H_ 32
#define HKV_ 8
#define DH_ 128
#define SCALE_ 0.08838834764831845f
#define M_FIX 20.0f
#define KEEP_ 512
#define O_ELEMS (B_*L_*H_*DH_)          // 16777216
#define CACHE_ELEMS (8192*HKV_*DH_)     // 8388608

typedef short short8 __attribute__((ext_vector_type(8)));
typedef float floatx4 __attribute__((ext_vector_type(4)));
typedef unsigned int uintx2 __attribute__((ext_vector_type(2)));
typedef unsigned int uintx4 __attribute__((ext_vector_type(4)));

__device__ inline unsigned short bf16r(float x) {
    unsigned int u = __builtin_bit_cast(unsigned int, x);
    u += 0x7fffu + ((u >> 16) & 1u);
    return (unsigned short)(u >> 16);
}
__device__ inline unsigned int pk_bf16(float a, float b) {
    return (unsigned int)bf16r(a) | ((unsigned int)bf16r(b) << 16);
}
__device__ inline float bf16tof(unsigned short h) {
    unsigned int u = ((unsigned int)h) << 16;
    return __builtin_bit_cast(float, u);
}

// ---------------- full causal attention, fixed-M bf16 MFMA flash ----------------
// grid 1024 = (b,h,pr); block 256 = 4 waves; phases qt=pr and qt=15-pr (uniform 17 tiles).
// LDS = 16K (K) + 16K (V^T) + 8K (P) = 40960 B -> 4 blocks/CU.
__global__ __launch_bounds__(256, 4)
void attn_mfma(const float* __restrict__ Qp, const float* __restrict__ Kp,
               const float* __restrict__ Vp, float* __restrict__ Op)
{
    __shared__ unsigned short k_lds[64 * 128];   // [col][d], 16B-granule XOR swizzle by col&15
    __shared__ unsigned short vT[128 * 64];      // [d][k],  granule XOR swizzle by d&7
    __shared__ unsigned short p_lds[4 * 1024];   // per-wave [m][k], granule XOR by m&7

    int bid = blockIdx.x;
    int pr = bid & 7;
    int h  = (bid >> 3) & 31;
    int b  = bid >> 8;
    int hkv = h >> 2;
    int t = threadIdx.x;
    int w = t >> 6;
    int l = t & 63;
    int lm = l & 15;
    int hq = l >> 4;

    for (int ph = 0; ph < 2; ++ph) {
        int qt = ph ? (15 - pr) : pr;

        // Q A-frags (scale folded): A[m=lm][k=hq*8+j+32kc]
        short8 aq[4];
        {
            const float* qb = Qp + ((size_t)(b * L_ + qt * 64 + w * 16 + lm) * H_ + h) * DH_;
            #pragma unroll
            for (int c = 0; c < 4; ++c) {
                int dc = hq * 8 + 32 * c;
                float4 x0 = *(const float4*)(qb + dc);
                float4 x1 = *(const float4*)(qb + dc + 4);
                uintx4 packed;
                packed[0] = pk_bf16(x0.x * SCALE_, x0.y * SCALE_);
                packed[1] = pk_bf16(x0.z * SCALE_, x0.w * SCALE_);
                packed[2] = pk_bf16(x1.x * SCALE_, x1.y * SCALE_);
                packed[3] = pk_bf16(x1.z * SCALE_, x1.w * SCALE_);
                aq[c] = __builtin_bit_cast(short8, packed);
            }
        }

        floatx4 O[8];
        #pragma unroll
        for (int n = 0; n < 8; ++n) O[n] = (floatx4){0.f, 0.f, 0.f, 0.f};
        float l_acc[4] = {0.f, 0.f, 0.f, 0.f};

        for (int kt = 0; kt <= qt; ++kt) {
            __syncthreads();
            // stage K: granule = 8 dims; coalesced 32B/lane reads
            #pragma unroll
            for (int i = 0; i < 4; ++i) {
                int pos = t + 256 * i;
                int col = pos >> 4, gd = pos & 15;
                const float* kb = &Kp[((size_t)(b * L_ + kt * 64 + col) * HKV_ + hkv) * DH_ + gd * 8];
                float4 x0 = *(const float4*)kb;
                float4 x1 = *(const float4*)(kb + 4);
                uintx4 g;
                g[0] = pk_bf16(x0.x, x0.y); g[1] = pk_bf16(x0.z, x0.w);
                g[2] = pk_bf16(x1.x, x1.y); g[3] = pk_bf16(x1.z, x1.w);
                int phys = gd ^ (col & 15);
                *(uintx4*)&k_lds[col * 128 + phys * 8] = g;
            }
            // stage V^T: lane handles (4 dims) x (8 k rows), two half-granule passes
            {
                int d4g = t & 31, rb8 = t >> 5;
                const float* vb = &Vp[((size_t)(b * L_ + kt * 64 + rb8 * 8) * HKV_ + hkv) * DH_ + d4g * 4];
                const size_t vs = (size_t)HKV_ * DH_;
                #pragma unroll
                for (int half = 0; half < 2; ++half) {
                    float4 e0 = *(const float4*)(vb + (size_t)(4 * half + 0) * vs);
                    float4 e1 = *(const float4*)(vb + (size_t)(4 * half + 1) * vs);
                    float4 e2 = *(const float4*)(vb + (size_t)(4 * half + 2) * vs);
                    float4 e3 = *(const float4*)(vb + (size_t)(4 * half + 3) * vs);
                    const float* f0 = (const float*)&e0;
                    const float* f1 = (const float*)&e1;
                    const float* f2 = (const float*)&e2;
                    const float* f3 = (const float*)&e3;
                    #pragma unroll
                    for (int ii = 0; ii < 4; ++ii) {
                        int d = d4g * 4 + ii;
                        int phys = rb8 ^ (d & 7);
                        uintx2 gp;
                        gp[0] = pk_bf16(f0[ii], f1[ii]);
                        gp[1] = pk_bf16(f2[ii], f3[ii]);
                        *(uintx2*)&vT[d * 64 + phys * 8 + half * 4] = gp;
                    }
                }
            }
            __syncthreads();

            // QK^T: S[c] col n=lm <-> k_phys = lm*4+c ; C-init = -M (fixed-M softmax)
            floatx4 S[4];
            #pragma unroll
            for (int c = 0; c < 4; ++c) S[c] = (floatx4){-M_FIX, -M_FIX, -M_FIX, -M_FIX};
            #pragma unroll
            for (int kc = 0; kc < 4; ++kc) {
                #pragma unroll
                for (int c = 0; c < 4; ++c) {
                    int row = lm * 4 + c;
                    int phys = (kc * 4 + hq) ^ (row & 15);
                    short8 bk = *(const short8*)&k_lds[row * 128 + phys * 8];
                    S[c] = __builtin_amdgcn_mfma_f32_16x16x32_bf16(aq[kc], bk, S[c], 0, 0, 0);
                }
            }
            bool diag = (kt == qt);
            #pragma unroll
            for (int r = 0; r < 4; ++r) {
                float e0 = __expf(S[0][r]);
                float e1 = __expf(S[1][r]);
                float e2 = __expf(S[2][r]);
                float e3 = __expf(S[3][r]);
                if (diag) {
                    int qabs = qt * 64 + w * 16 + hq * 4 + r;
                    int kb0 = kt * 64 + lm * 4;
                    e0 = (kb0 + 0 <= qabs) ? e0 : 0.f;
                    e1 = (kb0 + 1 <= qabs) ? e1 : 0.f;
                    e2 = (kb0 + 2 <= qabs) ? e2 : 0.f;
                    e3 = (kb0 + 3 <= qabs) ? e3 : 0.f;
                }
                l_acc[r] += (e0 + e1) + (e2 + e3);
                int m = hq * 4 + r;
                int phys = (lm >> 1) ^ (m & 7);
                uintx2 gp;
                gp[0] = pk_bf16(e0, e1);
                gp[1] = pk_bf16(e2, e3);
                *(uintx2*)&p_lds[w * 1024 + m * 64 + phys * 8 + (lm & 1) * 4] = gp;
            }
            asm volatile("" ::: "memory");
            // PV as O^T = V^T * P^T  (A = V^T frag, B = P^T frag)
            int phys0 = hq ^ (lm & 7);
            int phys1 = (4 + hq) ^ (lm & 7);
            short8 bp0 = *(const short8*)&p_lds[w * 1024 + lm * 64 + phys0 * 8];
            short8 bp1 = *(const short8*)&p_lds[w * 1024 + lm * 64 + phys1 * 8];
            #pragma unroll
            for (int n = 0; n < 8; ++n) {
                int d = n * 16 + lm;
                short8 a0 = *(const short8*)&vT[d * 64 + (hq ^ (d & 7)) * 8];
                O[n] = __builtin_amdgcn_mfma_f32_16x16x32_bf16(a0, bp0, O[n], 0, 0, 0);
                short8 a1 = *(const short8*)&vT[d * 64 + (((4 + hq) ^ (d & 7))) * 8];
                O[n] = __builtin_amdgcn_mfma_f32_16x16x32_bf16(a1, bp1, O[n], 0, 0, 0);
            }
        }
        // one-time l reduce + broadcast via p_lds (own-wave region)
        #pragma unroll
        for (int r = 0; r < 4; ++r) {
            l_acc[r] += __shfl_xor(l_acc[r], 1);
            l_acc[r] += __shfl_xor(l_acc[r], 2);
            l_acc[r] += __shfl_xor(l_acc[r], 4);
            l_acc[r] += __shfl_xor(l_acc[r], 8);
        }
        float* lf = (float*)&p_lds[w * 1024];
        if (lm == 0) {
            #pragma unroll
            for (int r = 0; r < 4; ++r) lf[hq * 4 + r] = l_acc[r];
        }
        asm volatile("" ::: "memory");
        __builtin_amdgcn_wave_barrier();
        float invl = 1.0f / lf[lm];
        // O^T epilogue: lane owns q = w*16+lm, d = n*16+hq*4..+3 -> float4 stores
        #pragma unroll
        for (int n = 0; n < 8; ++n) {
            float4 res;
            res.x = O[n][0] * invl; res.y = O[n][1] * invl;
            res.z = O[n][2] * invl; res.w = O[n][3] * invl;
            *(float4*)&Op[((size_t)(b * L_ + qt * 64 + w * 16 + lm) * H_ + h) * DH_ + n * 16 + hq * 4] = res;
        }
    }
}

// ---------------- importance kernel A: 1/L per sample row (split-bf16, fixed-M) ----------------
// grid 256 = (b,h,qts)
__global__ __launch_bounds__(256, 2)
void imp_l_kernel(const float* __restrict__ Qp, const float* __restrict__ Kp,
                  float* __restrict__ invL)
{
    __shared__ unsigned short khi[64 * 128];
    __shared__ unsigned short klo[64 * 128];

    int bid = blockIdx.x;
    int qts = bid & 1;
    int h   = (bid >> 1) & 31;
    int b   = bid >> 6;
    int hkv = h >> 2;
    int t = threadIdx.x;
    int w = t >> 6;
    int l = t & 63;
    int lm = l & 15;
    int hq = l >> 4;
    int q0 = 896 + qts * 64;
    int ktd = q0 >> 6;

    short8 aqh[4], aql[4];
    {
        const float* qb = Qp + ((size_t)(b * L_ + q0 + w * 16 + lm) * H_ + h) * DH_;
        #pragma unroll
        for (int c = 0; c < 4; ++c) {
            int dc = hq * 8 + 32 * c;
            float x[8];
            *(float4*)&x[0] = *(const float4*)(qb + dc);
            *(float4*)&x[4] = *(const float4*)(qb + dc + 4);
            short8 fh, fl;
            #pragma unroll
            for (int j = 0; j < 8; ++j) {
                float xs = x[j] * SCALE_;
                unsigned short hb = bf16r(xs);
                fh[j] = (short)hb;
                fl[j] = (short)bf16r(xs - bf16tof(hb));
            }
            aqh[c] = fh; aql[c] = fl;
        }
    }

    float l_acc[4] = {0.f, 0.f, 0.f, 0.f};
    for (int kt = 0; kt <= ktd; ++kt) {
        __syncthreads();
        #pragma unroll
        for (int i = 0; i < 4; ++i) {
            int pos = t + 256 * i;
            int col = pos >> 4, gd = pos & 15;
            const float* kb = &Kp[((size_t)(b * L_ + kt * 64 + col) * HKV_ + hkv) * DH_ + gd * 8];
            float x[8];
            *(float4*)&x[0] = *(const float4*)kb;
            *(float4*)&x[4] = *(const float4*)(kb + 4);
            unsigned int gh[4], gl[4];
            #pragma unroll
            for (int j = 0; j < 4; ++j) {
                unsigned short h0 = bf16r(x[2*j]),   h1 = bf16r(x[2*j+1]);
                unsigned short l0 = bf16r(x[2*j]   - bf16tof(h0));
                unsigned short l1 = bf16r(x[2*j+1] - bf16tof(h1));
                gh[j] = (unsigned int)h0 | ((unsigned int)h1 << 16);
                gl[j] = (unsigned int)l0 | ((unsigned int)l1 << 16);
            }
            int phys = gd ^ (col & 15);
            *(uintx4*)&khi[col * 128 + phys * 8] = (uintx4){gh[0], gh[1], gh[2], gh[3]};
            *(uintx4*)&klo[col * 128 + phys * 8] = (uintx4){gl[0], gl[1], gl[2], gl[3]};
        }
        __syncthreads();

        floatx4 S[4];
        #pragma unroll
        for (int c = 0; c < 4; ++c) S[c] = (floatx4){-M_FIX, -M_FIX, -M_FIX, -M_FIX};
        #pragma unroll
        for (int kc = 0; kc < 4; ++kc) {
            #pragma unroll
            for (int c = 0; c < 4; ++c) {
                int row = lm * 4 + c;
                int phys = (kc * 4 + hq) ^ (row & 15);
                short8 bh = *(const short8*)&khi[row * 128 + phys * 8];
                short8 bl = *(const short8*)&klo[row * 128 + phys * 8];
                S[c] = __builtin_amdgcn_mfma_f32_16x16x32_bf16(aqh[kc], bh, S[c], 0, 0, 0);
                S[c] = __builtin_amdgcn_mfma_f32_16x16x32_bf16(aqh[kc], bl, S[c], 0, 0, 0);
                S[c] = __builtin_amdgcn_mfma_f32_16x16x32_bf16(aql[kc], bh, S[c], 0, 0, 0);
            }
        }
        bool diag = (kt == ktd);
        #pragma unroll
        for (int r = 0; r < 4; ++r) {
            int qabs = q0 + w * 16 + hq * 4 + r;
            #pragma unroll
            for (int c = 0; c < 4; ++c) {
                float ev = __expf(S[c][r]);
                if (diag) {
                    int kabs = kt * 64 + lm * 4 + c;
                    ev = (kabs <= qabs) ? ev : 0.f;
                }
                l_acc[r] += ev;
            }
        }
    }
    #pragma unroll
    for (int r = 0; r < 4; ++r) {
        l_acc[r] += __shfl_xor(l_acc[r], 1);
        l_acc[r] += __shfl_xor(l_acc[r], 2);
        l_acc[r] += __shfl_xor(l_acc[r], 4);
        l_acc[r] += __shfl_xor(l_acc[r], 8);
    }
    if (lm == 0) {
        #pragma unroll
        for (int r = 0; r < 4; ++r)
            invL[((size_t)(b * H_ + h)) * 128 + qts * 64 + w * 16 + hq * 4 + r] = 1.0f / l_acc[r];
    }
}

// ---------------- importance kernel B: column sums per (b,h,kt) ----------------
// grid 2048 = (b,h,kt)
__global__ __launch_bounds__(256, 4)
void imp_col_kernel(const float* __restrict__ Qp, const float* __restrict__ Kp,
                    const float* __restrict__ invL, float* __restrict__ imp)
{
    __shared__ unsigned short khi[64 * 128];
    __shared__ unsigned short klo[64 * 128];
    __shared__ float imp_loc[64];

    int bid = blockIdx.x;
    int kt = bid & 15;
    int h  = (bid >> 4) & 31;
    int b  = bid >> 9;
    int hkv = h >> 2;
    int t = threadIdx.x;
    int w = t >> 6;
    int l = t & 63;
    int lm = l & 15;
    int hq = l >> 4;

    if (t < 64) imp_loc[t] = 0.f;
    #pragma unroll
    for (int i = 0; i < 4; ++i) {
        int pos = t + 256 * i;
        int col = pos >> 4, gd = pos & 15;
        const float* kb = &Kp[((size_t)(b * L_ + kt * 64 + col) * HKV_ + hkv) * DH_ + gd * 8];
        float x[8];
        *(float4*)&x[0] = *(const float4*)kb;
        *(float4*)&x[4] = *(const float4*)(kb + 4);
        unsigned int gh[4], gl[4];
        #pragma unroll
        for (int j = 0; j < 4; ++j) {
            unsigned short h0 = bf16r(x[2*j]),   h1 = bf16r(x[2*j+1]);
            unsigned short l0 = bf16r(x[2*j]   - bf16tof(h0));
            unsigned short l1 = bf16r(x[2*j+1] - bf16tof(h1));
            gh[j] = (unsigned int)h0 | ((unsigned int)h1 << 16);
            gl[j] = (unsigned int)l0 | ((unsigned int)l1 << 16);
        }
        int phys = gd ^ (col & 15);
        *(uintx4*)&khi[col * 128 + phys * 8] = (uintx4){gh[0], gh[1], gh[2], gh[3]};
        *(uintx4*)&klo[col * 128 + phys * 8] = (uintx4){gl[0], gl[1], gl[2], gl[3]};
    }
    __syncthreads();

    float cs[4] = {0.f, 0.f, 0.f, 0.f};
    for (int qp2 = 0; qp2 < 2; ++qp2) {
        if (kt == 15 && qp2 == 0) continue;
        int q0 = 896 + qp2 * 64;
        short8 aqh[4], aql[4];
        {
            const float* qb = Qp + ((size_t)(b * L_ + q0 + w * 16 + lm) * H_ + h) * DH_;
            #pragma unroll
            for (int c = 0; c < 4; ++c) {
                int dc = hq * 8 + 32 * c;
                float x[8];
                *(float4*)&x[0] = *(const float4*)(qb + dc);
                *(float4*)&x[4] = *(const float4*)(qb + dc + 4);
                short8 fh, fl;
                #pragma unroll
                for (int j = 0; j < 8; ++j) {
                    float xs = x[j] * SCALE_;
                    unsigned short hb = bf16r(xs);
                    fh[j] = (short)hb;
                    fl[j] = (short)bf16r(xs - bf16tof(hb));
                }
                aqh[c] = fh; aql[c] = fl;
            }
        }
        floatx4 iv4 = *(const floatx4*)&invL[((size_t)(b * H_ + h)) * 128 + qp2 * 64 + w * 16 + hq * 4];

        floatx4 S[4];
        #pragma unroll
        for (int c = 0; c < 4; ++c) S[c] = (floatx4){-M_FIX, -M_FIX, -M_FIX, -M_FIX};
        #pragma unroll
        for (int kc = 0; kc < 4; ++kc) {
            #pragma unroll
            for (int c = 0; c < 4; ++c) {
                int row = lm * 4 + c;
                int phys = (kc * 4 + hq) ^ (row & 15);
                short8 bh = *(const short8*)&khi[row * 128 + phys * 8];
                short8 bl = *(const short8*)&klo[row * 128 + phys * 8];
                S[c] = __builtin_amdgcn_mfma_f32_16x16x32_bf16(aqh[kc], bh, S[c], 0, 0, 0);
                S[c] = __builtin_amdgcn_mfma_f32_16x16x32_bf16(aqh[kc], bl, S[c], 0, 0, 0);
                S[c] = __builtin_amdgcn_mfma_f32_16x16x32_bf16(aql[kc], bh, S[c], 0, 0, 0);
            }
        }
        #pragma unroll
        for (int c = 0; c < 4; ++c) {
            int kabs = kt * 64 + lm * 4 + c;
            #pragma unroll
            for (int r = 0; r < 4; ++r) {
                int qabs = q0 + w * 16 + hq * 4 + r;
                float ev = (kabs <= qabs) ? __expf(S[c][r]) : 0.f;
                cs[c] += ev * iv4[r];
            }
        }
    }
    #pragma unroll
    for (int c = 0; c < 4; ++c) {
        cs[c] += __shfl_xor(cs[c], 16);
        cs[c] += __shfl_xor(cs[c], 32);
    }
    if (l < 16) {
        #pragma unroll
        for (int c = 0; c < 4; ++c) atomicAdd(&imp_loc[lm * 4 + c], cs[c]);
    }
    __syncthreads();
    if (t < 64) atomicAdd(&imp[b * L_ + kt * 64 + t], imp_loc[t]);
}

// ---------------- top-k 512 of 1024 per batch ----------------
__global__ void topk_kernel(const float* __restrict__ imp, int* __restrict__ keep)
{
    __shared__ float vals[1024];
    __shared__ int   idxs[1024];
    int b = blockIdx.x;
    int t = threadIdx.x;   // 512 threads
    for (int i = t; i < 1024; i += 512) { vals[i] = imp[b * L_ + i]; idxs[i] = i; }

    for (int size = 2; size <= 1024; size <<= 1) {
        for (int stride = size >> 1; stride > 0; stride >>= 1) {
            __syncthreads();
            for (int i = t; i < 1024; i += 512) {
                int j = i ^ stride;
                if (j > i) {
                    float vi = vals[i], vj = vals[j];
                    int ii = idxs[i], ij = idxs[j];
                    bool j_before_i = (vj > vi) || (vj == vi && ij < ii);
                    bool descRegion = ((i & size) == 0);
                    bool doSwap = descRegion ? j_before_i : !j_before_i;
                    if (doSwap) {
                        vals[i] = vj; vals[j] = vi;
                        idxs[i] = ij; idxs[j] = ii;
                    }
                }
            }
        }
    }
    __syncthreads();
    for (int size = 2; size <= 512; size <<= 1) {
        for (int stride = size >> 1; stride > 0; stride >>= 1) {
            __syncthreads();
            int i = t, j = t ^ stride;
            if (j > i) {
                int a = idxs[i], bb = idxs[j];
                bool ascRegion = ((i & size) == 0);
                bool doSwap = ascRegion ? (a > bb) : (a < bb);
                if (doSwap) { idxs[i] = bb; idxs[j] = a; }
            }
        }
    }
    __syncthreads();
    keep[b * KEEP_ + t] = idxs[t];
}

// ---------------- scatter kept k/v rows into caches ----------------
__global__ void scatter_kernel(const float* __restrict__ kin, const float* __restrict__ vin,
                               const int* __restrict__ keep, const int* __restrict__ slot_mapping,
                               float* __restrict__ kc_out, float* __restrict__ vc_out)
{
    int bid = blockIdx.x;          // 2048 = b*512 + j
    int b = bid >> 9, j = bid & 511;
    int src = b * L_ + keep[b * KEEP_ + j];
    int dst = slot_mapping[b * L_ + j];
    int t = threadIdx.x;           // 256, float4 each = 1024 floats
    float4 kv = *(const float4*)&kin[(size_t)src * 1024 + t * 4];
    *(float4*)&kc_out[(size_t)dst * 1024 + t * 4] = kv;
    float4 vv = *(const float4*)&vin[(size_t)src * 1024 + t * 4];
    *(float4*)&vc_out[(size_t)dst * 1024 + t * 4] = vv;
}

extern "C" void kernel_launch(void* const* d_in, const int* in_sizes, int n_in,
                              void* d_out, int out_size, void* d_ws, size_t ws_size,
                              hipStream_t stream)
{
    const float* q = (const float*)d_in[0];
    const float* k = (const float*)d_in[1];
    const float* v = (const float*)d_in[2];
    const float* k_cache = (const float*)d_in[3];
    const float* v_cache = (const float*)d_in[4];
    const int* slot_mapping = (const int*)d_in[5];

    float* o = (float*)d_out;
    float* kc_out = o + O_ELEMS;
    float* vc_out = kc_out + CACHE_ELEMS;

    float* imp  = (float*)d_ws;                    // 4096 f
    int*   keep = (int*)(imp + B_ * L_);           // 2048 i
    float* invL = (float*)(keep + B_ * KEEP_);     // 16384 f

    (void)hipMemcpyAsync(kc_out, k_cache, (size_t)CACHE_ELEMS * 4, hipMemcpyDeviceToDevice, stream);
    (void)hipMemcpyAsync(vc_out, v_cache, (size_t)CACHE_ELEMS * 4, hipMemcpyDeviceToDevice, stream);
    (void)hipMemsetAsync(imp, 0, B_ * L_ * 4, stream);

    attn_mfma<<<dim3(1024), dim3(256), 0, stream>>>(q, k, v, o);
    imp_l_kernel<<<dim3(256), dim3(256), 0, stream>>>(q, k, invL);
    imp_col_kernel<<<dim3(2048), dim3(256), 0, stream>>>(q, k, invL, imp);
    topk_kernel<<<dim3(4), dim3(512), 0, stream>>>(imp, keep);
    scatter_kernel<<<dim3(2048), dim3(256), 0, stream>>>(k, v, keep, slot_mapping, kc_out, vc_out);
}